// Round 3
// baseline (204.917 us; speedup 1.0000x reference)
//
#include <hip/hip_runtime.h>
#include <stdint.h>

typedef __attribute__((ext_vector_type(8))) short shortx8;
typedef __attribute__((ext_vector_type(4))) float floatx4;

static constexpr int SEQ_    = 2048;
static constexpr int DMODEL  = 1024;
static constexpr int HDIM    = 64;
static constexpr int BATCH_  = 2;
static constexpr int NHEADS  = 16;
static constexpr int WINDOW_ = 64;
static constexpr int GTOK    = 4;
static constexpr int RTOK    = 32;
static constexpr int ROWS    = BATCH_ * SEQ_;   // 4096
static constexpr int QKVN    = 3 * DMODEL;      // 3072

__device__ inline unsigned short f2bf(float f) {
  union { float f; unsigned int u; } x; x.f = f;
  unsigned int r = (x.u + 0x7FFFu + ((x.u >> 16) & 1u)) >> 16;
  return (unsigned short)r;
}
__device__ inline float bf2f(unsigned short b) {
  union { unsigned int u; float f; } x; x.u = ((unsigned int)b) << 16;
  return x.f;
}

__device__ inline void gload_lds16(const void* g, void* l) {
  __builtin_amdgcn_global_load_lds(
      (const __attribute__((address_space(1))) void*)g,
      (__attribute__((address_space(3))) void*)l, 16, 0, 0);
}

// ---------------- LayerNorm -> bf16 ----------------
__global__ __launch_bounds__(256) void ln_kernel(const float* __restrict__ x,
    const float* __restrict__ gamma, const float* __restrict__ beta,
    unsigned short* __restrict__ xn) {
  int row = blockIdx.x;
  int t = threadIdx.x;
  const float4* xr = (const float4*)(x + (size_t)row * DMODEL);
  float4 v = xr[t];
  float s = v.x + v.y + v.z + v.w;
  #pragma unroll
  for (int o = 32; o > 0; o >>= 1) s += __shfl_xor(s, o);
  __shared__ float red[4];
  __shared__ float red2[4];
  int wave = t >> 6, lane = t & 63;
  if (lane == 0) red[wave] = s;
  __syncthreads();
  float mean = (red[0] + red[1] + red[2] + red[3]) * (1.0f / DMODEL);
  float dx = v.x - mean, dy = v.y - mean, dz = v.z - mean, dw = v.w - mean;
  float q = dx*dx + dy*dy + dz*dz + dw*dw;
  #pragma unroll
  for (int o = 32; o > 0; o >>= 1) q += __shfl_xor(q, o);
  if (lane == 0) red2[wave] = q;
  __syncthreads();
  float var = (red2[0] + red2[1] + red2[2] + red2[3]) * (1.0f / DMODEL);
  float rs = rsqrtf(var + 1e-5f);
  float4 g = ((const float4*)gamma)[t];
  float4 bb = ((const float4*)beta)[t];
  ushort4 outv;
  outv.x = f2bf(dx * rs * g.x + bb.x);
  outv.y = f2bf(dy * rs * g.y + bb.y);
  outv.z = f2bf(dz * rs * g.z + bb.z);
  outv.w = f2bf(dw * rs * g.w + bb.w);
  ((ushort4*)(xn + (size_t)row * DMODEL))[t] = outv;
}

// ---------------- transpose + convert: src[K][N] fp32 -> dst[N][K] bf16 ----------------
__global__ __launch_bounds__(256) void cvtT_kernel(const float* __restrict__ src,
    unsigned short* __restrict__ dst, int K, int N) {
  __shared__ float tile[32][33];
  int k0 = blockIdx.y * 32, n0 = blockIdx.x * 32;
  int tx = threadIdx.x & 31, ty = threadIdx.x >> 5;  // 32x8
  #pragma unroll
  for (int r = ty; r < 32; r += 8)
    tile[r][tx] = src[(size_t)(k0 + r) * N + n0 + tx];
  __syncthreads();
  #pragma unroll
  for (int r = ty; r < 32; r += 8)
    dst[(size_t)(n0 + r) * K + k0 + tx] = f2bf(tile[tx][r]);
}

// ---------------- bf16 MFMA GEMM: C[M x 1024] = A[MxK] @ BT[1024xK]^T (+resid) ------
// BM=128, BN=64, BK=32, 256 thr = 4 waves (2x2), wave tile 64x32 (4x2 of 16x16x32).
// 512 blocks -> 2 blocks/CU. global_load_lds width=16 (layout forced contiguous).
__global__ __launch_bounds__(256) void gemm128x64(
    const unsigned short* __restrict__ A, const unsigned short* __restrict__ BT,
    unsigned short* __restrict__ Cb, float* __restrict__ Cf,
    const float* __restrict__ resid, int M, int N, int K, int ldc) {
  __shared__ unsigned short Al[128 * 32];
  __shared__ unsigned short Bl[64 * 32];
  const int bm = blockIdx.y * 128, bn = blockIdx.x * 64;
  const int tid = threadIdx.x;
  const int wave = tid >> 6, lane = tid & 63;
  const int wm = (wave >> 1) * 64, wn = (wave & 1) * 32;
  const int quad = lane >> 4, l16 = lane & 15;
  const int lrow = lane >> 2;          // 16 rows per 1KB inst, 4 lanes/row
  const int lkoff = (lane & 3) * 8;    // 8 bf16 = 16B per lane
  floatx4 acc[4][2] = {};
  for (int k0 = 0; k0 < K; k0 += 32) {
    __syncthreads();
    #pragma unroll
    for (int q = 0; q < 2; q++) {       // A: 128 rows, wave stages 32
      int r = wave * 32 + q * 16;
      gload_lds16(A + (size_t)(bm + r + lrow) * K + k0 + lkoff, Al + r * 32);
    }
    {                                   // B: 64 rows, wave stages 16
      int r = wave * 16;
      gload_lds16(BT + (size_t)(bn + r + lrow) * K + k0 + lkoff, Bl + r * 32);
    }
    __syncthreads();
    shortx8 af[4], bfr[2];
    #pragma unroll
    for (int s = 0; s < 4; s++)
      af[s] = *(const shortx8*)&Al[(wm + s * 16 + l16) * 32 + quad * 8];
    #pragma unroll
    for (int s = 0; s < 2; s++)
      bfr[s] = *(const shortx8*)&Bl[(wn + s * 16 + l16) * 32 + quad * 8];
    #pragma unroll
    for (int sm = 0; sm < 4; sm++)
      #pragma unroll
      for (int sn = 0; sn < 2; sn++)
        acc[sm][sn] = __builtin_amdgcn_mfma_f32_16x16x32_bf16(af[sm], bfr[sn], acc[sm][sn], 0, 0, 0);
  }
  #pragma unroll
  for (int sm = 0; sm < 4; sm++)
    #pragma unroll
    for (int sn = 0; sn < 2; sn++)
      #pragma unroll
      for (int r = 0; r < 4; r++) {
        int row = bm + wm + sm * 16 + quad * 4 + r;
        int col = bn + wn + sn * 16 + l16;
        size_t off = (size_t)row * ldc + col;
        float v = acc[sm][sn][r];
        if (resid) v += resid[off];
        if (Cf) Cf[off] = v;
        else    Cb[off] = f2bf(v);
      }
}

// ---------------- per-row top-tier mask column lists ----------------
__global__ __launch_bounds__(64) void mask_rows(const int* __restrict__ rand_idx,
    int* __restrict__ cols, int* __restrict__ cnt, int* __restrict__ tmx) {
  const int i = blockIdx.x;
  const int lane = threadIdx.x;
  __shared__ int rl[RTOK];
  __shared__ int scount;
  if (lane < RTOK) rl[lane] = rand_idx[i * RTOK + lane];
  if (lane == 0) scount = 0;
  __syncthreads();
  const int wstart = (i - WINDOW_ > 0) ? (i - WINDOW_) : 0;
  int jj[2]; int tt[2];
  #pragma unroll
  for (int p = 0; p < 2; p++) {
    int c = lane + p * 64;
    int j = -1;
    bool valid = false;
    if (c < 65) {
      j = i - WINDOW_ + c;
      valid = (j >= 0);
    } else if (c < 73) {
      int g = c - 65;
      j = (g < 4) ? g : (SEQ_ - 8 + g);
      valid = (j <= i) && (j < wstart);
    } else if (c < 73 + RTOK) {
      int r = c - 73;
      j = rl[r];
      bool dup = false;
      for (int r2 = 0; r2 < r; r2++) dup = dup || (rl[r2] == j);
      valid = (j <= i) && (j < wstart) && !(j < GTOK || j >= SEQ_ - GTOK) && !dup;
    }
    int t = -1;
    if (valid) {
      int loc = ((i - j) <= WINDOW_) ? 1 : 0;
      int glb = (j < GTOK || j >= SEQ_ - GTOK) ? 1 : 0;
      int rnd = 0;
      for (int r = 0; r < RTOK; r++) rnd |= (rl[r] == j) ? 1 : 0;
      t = loc + glb + rnd;
    }
    jj[p] = j; tt[p] = t;
  }
  int tm = (tt[0] > tt[1]) ? tt[0] : tt[1];
  #pragma unroll
  for (int o = 1; o < 64; o <<= 1) {
    int other = __shfl_xor(tm, o);
    tm = (other > tm) ? other : tm;
  }
  #pragma unroll
  for (int p = 0; p < 2; p++) {
    if (tt[p] == tm) {
      int pos = atomicAdd(&scount, 1);
      cols[i * 128 + pos] = jj[p];
    }
  }
  __syncthreads();
  if (lane == 0) { cnt[i] = scount; tmx[i] = tm; }
}

// ---------------- tier-3 q/k fixup GEMV ----------------
// tier-3 rows are a subset of i in [0,68) u [2044,2048) (need global & window & random
// overlap). For each such row: q[i] and k[j] for its <=8 tier-3 cols, written into
// the same qkv buffer layout the V-GEMM fills, so attn is oblivious.
__global__ __launch_bounds__(256) void qk_fix(
    const unsigned short* __restrict__ xn, const unsigned short* __restrict__ wqT,
    const int* __restrict__ cols, const int* __restrict__ cnt, const int* __restrict__ tmx,
    unsigned short* __restrict__ qkv) {
  const int bx = blockIdx.x;
  const int i = (bx < 68) ? bx : (SEQ_ - 4 + (bx - 68));
  if (tmx[i] != 3) return;
  const int b = blockIdx.y, h = blockIdx.z;
  const int n = cnt[i];
  const int wave = threadIdx.x >> 6, lane = threadIdx.x & 63;
  for (int t = wave; t <= n; t += 4) {   // t=0 -> q row i; t>=1 -> k row cols[t-1]
    int srcrow, woff;
    if (t == 0) { srcrow = i; woff = 0; }
    else        { srcrow = cols[i * 128 + (t - 1)]; woff = DMODEL; }
    const shortx8* xr = (const shortx8*)(xn + (size_t)(b * SEQ_ + srcrow) * DMODEL);
    const shortx8* wr = (const shortx8*)(wqT + (size_t)(woff + h * HDIM + lane) * DMODEL);
    float acc = 0.f;
    for (int kk = 0; kk < DMODEL / 8; kk++) {
      shortx8 xv = xr[kk], wv = wr[kk];
      #pragma unroll
      for (int e = 0; e < 8; e++)
        acc += bf2f((unsigned short)xv[e]) * bf2f((unsigned short)wv[e]);
    }
    qkv[(size_t)(b * SEQ_ + srcrow) * QKVN + woff + h * HDIM + lane] = f2bf(acc);
  }
}

// ---------------- sparse attention: one block per (b,row), all 16 heads ----------------
__global__ __launch_bounds__(256) void attn_v2(
    const unsigned short* __restrict__ qkv, const int* __restrict__ cols,
    const int* __restrict__ cnt, const int* __restrict__ tmx,
    unsigned short* __restrict__ ao) {
  const int i = blockIdx.x, b = blockIdx.y;
  const int t = threadIdx.x;
  const int n = cnt[i], tm = tmx[i];
  __shared__ int cj[128];
  __shared__ float sw[4][128];
  for (int c = t; c < n; c += 256) cj[c] = cols[i * 128 + c];
  __syncthreads();
  const size_t base = (size_t)(b * SEQ_) * QKVN;
  if (tm < 3) {
    // uniform over top-tier cols; V only. 4-way unroll: 4 loads in flight / wave.
    const ushort4* vbase = (const ushort4*)(qkv + base + 2 * DMODEL); // row stride 768 u4
    float4 s0 = {0,0,0,0}, s1 = {0,0,0,0}, s2 = {0,0,0,0}, s3 = {0,0,0,0};
    int c = 0;
    for (; c + 4 <= n; c += 4) {
      int j0 = cj[c], j1 = cj[c+1], j2 = cj[c+2], j3 = cj[c+3];
      ushort4 a0 = vbase[(size_t)j0 * 768 + t];
      ushort4 a1 = vbase[(size_t)j1 * 768 + t];
      ushort4 a2 = vbase[(size_t)j2 * 768 + t];
      ushort4 a3 = vbase[(size_t)j3 * 768 + t];
      s0.x += bf2f(a0.x); s0.y += bf2f(a0.y); s0.z += bf2f(a0.z); s0.w += bf2f(a0.w);
      s1.x += bf2f(a1.x); s1.y += bf2f(a1.y); s1.z += bf2f(a1.z); s1.w += bf2f(a1.w);
      s2.x += bf2f(a2.x); s2.y += bf2f(a2.y); s2.z += bf2f(a2.z); s2.w += bf2f(a2.w);
      s3.x += bf2f(a3.x); s3.y += bf2f(a3.y); s3.z += bf2f(a3.z); s3.w += bf2f(a3.w);
    }
    for (; c < n; c++) {
      ushort4 a0 = vbase[(size_t)cj[c] * 768 + t];
      s0.x += bf2f(a0.x); s0.y += bf2f(a0.y); s0.z += bf2f(a0.z); s0.w += bf2f(a0.w);
    }
    float inv = 1.0f / (float)n;
    ushort4 o;
    o.x = f2bf((s0.x + s1.x + s2.x + s3.x) * inv);
    o.y = f2bf((s0.y + s1.y + s2.y + s3.y) * inv);
    o.z = f2bf((s0.z + s1.z + s2.z + s3.z) * inv);
    o.w = f2bf((s0.w + s1.w + s2.w + s3.w) * inv);
    ((ushort4*)(ao + (size_t)(b * SEQ_ + i) * DMODEL))[t] = o;
  } else {
    // rare tier-3 rows: true softmax of 3*qk/8 per head. wave w -> heads w, w+4, ...
    const int wave = t >> 6, lane = t & 63;
    for (int h = wave; h < NHEADS; h += 4) {
      const size_t rb = base + (size_t)h * HDIM + lane;
      float qd = bf2f(qkv[rb + (size_t)i * QKVN]);
      float m = -1e30f;
      for (int c = 0; c < n; c++) {
        float kd = bf2f(qkv[rb + (size_t)cj[c] * QKVN + DMODEL]);
        float p = qd * kd;
        #pragma unroll
        for (int o = 32; o > 0; o >>= 1) p += __shfl_xor(p, o);
        p *= 0.375f;   // 3 * (qk/8)
        sw[wave][c] = p;
        m = fmaxf(m, p);
      }
      float denom = 0.f, acc = 0.f;
      for (int c = 0; c < n; c++) {
        float w = __expf(sw[wave][c] - m);
        denom += w;
        acc += w * bf2f(qkv[rb + (size_t)cj[c] * QKVN + 2 * DMODEL]);
      }
      ao[(size_t)(b * SEQ_ + i) * DMODEL + h * HDIM + lane] = f2bf(acc / denom);
    }
  }
}

extern "C" void kernel_launch(void* const* d_in, const int* in_sizes, int n_in,
                              void* d_out, int out_size, void* d_ws, size_t ws_size,
                              hipStream_t stream) {
  const float* x     = (const float*)d_in[0];
  const float* w_qkv = (const float*)d_in[1];
  const float* w_out = (const float*)d_in[2];
  const float* gamma = (const float*)d_in[3];
  const float* beta  = (const float*)d_in[4];
  const int*   ridx  = (const int*)d_in[5];
  float* out = (float*)d_out;

  char* ws = (char*)d_ws;
  size_t off = 0;
  auto alloc = [&](size_t bytes) {
    char* p = ws + off;
    off = (off + bytes + 255) & ~(size_t)255;
    return p;
  };
  unsigned short* xn   = (unsigned short*)alloc((size_t)ROWS * DMODEL * 2);   // 8 MB
  unsigned short* wqT  = (unsigned short*)alloc((size_t)QKVN * DMODEL * 2);   // 6 MB (N x K)
  unsigned short* woT  = (unsigned short*)alloc((size_t)DMODEL * DMODEL * 2); // 2 MB (N x K)
  unsigned short* qkv  = (unsigned short*)alloc((size_t)ROWS * QKVN * 2);     // 24 MB
  unsigned short* ao   = (unsigned short*)alloc((size_t)ROWS * DMODEL * 2);   // 8 MB
  int* cols = (int*)alloc((size_t)SEQ_ * 128 * 4);                            // 1 MB
  int* cnt  = (int*)alloc((size_t)SEQ_ * 4);
  int* tmx  = (int*)alloc((size_t)SEQ_ * 4);

  hipLaunchKernelGGL(ln_kernel, dim3(ROWS), dim3(256), 0, stream, x, gamma, beta, xn);
  hipLaunchKernelGGL(cvtT_kernel, dim3(QKVN / 32, DMODEL / 32), dim3(256), 0, stream,
                     w_qkv, wqT, DMODEL, QKVN);
  hipLaunchKernelGGL(cvtT_kernel, dim3(DMODEL / 32, DMODEL / 32), dim3(256), 0, stream,
                     w_out, woT, DMODEL, DMODEL);
  hipLaunchKernelGGL(mask_rows, dim3(SEQ_), dim3(64), 0, stream, ridx, cols, cnt, tmx);
  // V-only projection: BT = V-rows of wqT; C = qkv at col offset 2*DMODEL, ldc=3072
  hipLaunchKernelGGL(gemm128x64, dim3(DMODEL / 64, ROWS / 128), dim3(256), 0, stream,
                     xn, wqT + (size_t)2 * DMODEL * DMODEL, qkv + 2 * DMODEL, (float*)nullptr,
                     (const float*)nullptr, ROWS, DMODEL, DMODEL, QKVN);
  hipLaunchKernelGGL(qk_fix, dim3(72, BATCH_, NHEADS), dim3(256), 0, stream,
                     xn, wqT, cols, cnt, tmx, qkv);
  hipLaunchKernelGGL(attn_v2, dim3(SEQ_, BATCH_), dim3(256), 0, stream,
                     qkv, cols, cnt, tmx, ao);
  hipLaunchKernelGGL(gemm128x64, dim3(DMODEL / 64, ROWS / 128), dim3(256), 0, stream,
                     ao, woT, (unsigned short*)nullptr, out, x, ROWS, DMODEL, DMODEL, DMODEL);
}